// Round 4
// baseline (410.732 us; speedup 1.0000x reference)
//
#include <hip/hip_runtime.h>
#include <hip/hip_fp16.h>

#define N_NODES 8192
#define DEG     16
#define NEDGE   (N_NODES*DEG)
#define F       128
#define F3      384
#define RBF     20
#define NLAYER  3
#define NF      (N_NODES*F)
#define PI_F    3.14159265358979f

typedef unsigned short u16;
typedef __bf16 bf16x8 __attribute__((ext_vector_type(8)));
typedef float  f32x4  __attribute__((ext_vector_type(4)));
typedef _Float16 f16x2 __attribute__((ext_vector_type(2)));

__device__ __forceinline__ float bf2f(u16 u){ return __uint_as_float(((unsigned)u)<<16); }
__device__ __forceinline__ u16 f2bf(float f){
  unsigned x = __float_as_uint(f);
  unsigned r = (x + 0x7FFFu + ((x>>16)&1u)) >> 16;   // RNE
  return (u16)r;
}
__device__ __forceinline__ float lo_bf(unsigned u){ return __uint_as_float(u<<16); }
__device__ __forceinline__ float hi_bf(unsigned u){ return __uint_as_float(u & 0xFFFF0000u); }
__device__ __forceinline__ float silu_f(float x){ return x / (1.f + __expf(-x)); }
__device__ __forceinline__ float ldsrc(const void* src, int i, int bf){
  return bf ? bf2f(((const u16*)src)[i]) : ((const float*)src)[i];
}
__device__ __forceinline__ unsigned packh2(float a, float b){
  return (unsigned)__half_as_ushort(__float2half(a)) |
         ((unsigned)__half_as_ushort(__float2half(b)) << 16);
}
// v_dot2_f32_f16: c += a.x*b.x + a.y*b.y  (fp32 accumulate, 1 VALU op)
__device__ __forceinline__ float fdot2u(unsigned a, unsigned b, float c){
  return __builtin_amdgcn_fdot2(__builtin_bit_cast(f16x2, a),
                                __builtin_bit_cast(f16x2, b), c, false);
}

// ------------------------------------------------------------ dtype detect
__global__ void k_detect(const u16* __restrict__ rd, int* __restrict__ flag){
  if (threadIdx.x == 0 && blockIdx.x == 0){
    int ok = 1;
    for (int i = 0; i < 128; i++){
      float v = bf2f(rd[2*i]);
      if (!(v > 0.01f && v < 4.0f)) { ok = 0; break; }
    }
    *flag = ok;   // 1 = inputs bf16, 0 = fp32
  }
}

// ------------------------------------------- split helper: [L][K][N] -> [L][N][K] hi/lo
__device__ __forceinline__ void splitw(const void* src, u16* bh, u16* bl,
                                       int i, int K, int Ncol, int bf){
  int kn = K*Ncol; int l = i/kn; int r = i - l*kn; int k = r/Ncol; int n = r - k*Ncol;
  float w = ldsrc(src, i, bf);
  u16 h = f2bf(w);
  size_t o = (size_t)l*kn + (size_t)n*K + k;
  bh[o] = h; bl[o] = f2bf(w - bf2f(h));
}

// -------------------------------------- fused preamble (weights + edges + node init)
__global__ __launch_bounds__(256) void k_prep(
    const void* mb1, const void* mb2, const void* b1, const void* b2,
    const void* rw,  const void* rb,
    const void* mw1, const void* mw2, const void* w1, const void* w2,
    const void* Uw,  const void* Vw,
    const void* dist, const void* dirv, const int* __restrict__ idxj,
    const int* __restrict__ atoms, const void* __restrict__ emb,
    float* c_mb1, float* c_mb2, float* c_b1, float* c_b2,
    unsigned* rwp2,                 // [L][11][3F]
    u16* mw1h, u16* mw1l, u16* mw2h, u16* mw2l, u16* w1h, u16* w1l,
    u16* w2h, u16* w2l, u16* uvh, u16* uvl,
    uint4* edata,                   // [E][4]
    float* s, u16* s_h, u16* s_l,
    u16* p0h, u16* p0l, u16* bufA16, u16* bufB16,
    const int* __restrict__ flag){
  int i = blockIdx.x*256 + threadIdx.x;
  int bf = *flag;
  const int S0=NLAYER*F, S1=NLAYER*F3, S2=NLAYER*F, S3=NLAYER*F3;
  const int S4=NLAYER*11*F3;
  const int S5=NLAYER*F*F, S6=NLAYER*F*F3, S7=NLAYER*2*F*F, S8=NLAYER*F*F3, S9=NLAYER*256*F;
  if (i < S0){ c_mb1[i]=ldsrc(mb1,i,bf); return; } i-=S0;
  if (i < S1){ c_mb2[i]=ldsrc(mb2,i,bf); return; } i-=S1;
  if (i < S2){ c_b1[i] =ldsrc(b1, i,bf); return; } i-=S2;
  if (i < S3){ c_b2[i] =ldsrc(b2, i,bf); return; } i-=S3;
  if (i < S4){
    int l = i/(11*F3); int r = i - l*(11*F3); int r2 = r/F3; int col = r - r2*F3;
    float w0, w1v;
    if (r2 < 10){
      w0  = ldsrc(rw, (l*RBF + 2*r2  )*F3 + col, bf);
      w1v = ldsrc(rw, (l*RBF + 2*r2+1)*F3 + col, bf);
    } else {
      w0  = ldsrc(rb, l*F3 + col, bf);
      w1v = 0.f;
    }
    rwp2[i] = packh2(w0, w1v);
    return;
  } i-=S4;
  if (i < S5){ splitw(mw1, mw1h, mw1l, i, F,   F,  bf); return; } i-=S5;
  if (i < S6){ splitw(mw2, mw2h, mw2l, i, F,   F3, bf); return; } i-=S6;
  if (i < S7){ splitw(w1,  w1h,  w1l,  i, 2*F, F,  bf); return; } i-=S7;
  if (i < S8){ splitw(w2,  w2h,  w2l,  i, F,   F3, bf); return; } i-=S8;
  if (i < S9){
    int l=i/(256*F); int r=i-l*(256*F); int n=r>>7; int k=r&127;
    int si=(l*F+k)*F+(n&127);
    float w = ldsrc((n<128)?Uw:Vw, si, bf);
    u16 h=f2bf(w); uvh[i]=h; uvl[i]=f2bf(w-bf2f(h));
    return;
  } i-=S9;
  if (i < NEDGE){
    int e = i;
    float d = ldsrc(dist, e, bf);
    float th = PI_F*d*(1.f/3.f);
    float c  = __cosf(th);
    float s1 = __sinf(th);
    float cut = 0.5f*(c + 1.0f);
    float ic = cut/d;
    // Chebyshev recurrence: sin((k+1)th) = 2c*sin(k th) - sin((k-1) th)
    float sk[RBF+1];
    sk[0] = s1; float sm1 = 0.f, s0 = s1;
    #pragma unroll
    for (int k=1;k<=RBF;k++){ float sn = 2.f*c*s0 - sm1; sk[k-1] = s0; sm1 = s0; s0 = sn; }
    unsigned o[16];
    #pragma unroll
    for (int r2=0;r2<10;r2++)
      o[r2] = packh2(sk[2*r2]*ic, sk[2*r2+1]*ic);
    o[10] = packh2(cut, 0.f);
    o[11] = __float_as_uint(ldsrc(dirv, e*3+0, bf));
    o[12] = __float_as_uint(ldsrc(dirv, e*3+1, bf));
    o[13] = __float_as_uint(ldsrc(dirv, e*3+2, bf));
    o[14] = (unsigned)idxj[e];
    o[15] = 0;
    uint4* dst = edata + (size_t)e*4;
    dst[0] = make_uint4(o[0],o[1],o[2],o[3]);
    dst[1] = make_uint4(o[4],o[5],o[6],o[7]);
    dst[2] = make_uint4(o[8],o[9],o[10],o[11]);
    dst[3] = make_uint4(o[12],o[13],o[14],o[15]);
    return;
  } i-=NEDGE;
  if (i < NF){                      // node init
    int n = i >> 7, f = i & 127;
    float sv = ldsrc(emb, atoms[n]*F + f, bf);
    s[i] = sv;
    u16 hb = f2bf(sv); s_h[i] = hb; s_l[i] = f2bf(sv - bf2f(hb));
    p0h[i]=0; p0h[NF+i]=0; p0h[2*(size_t)NF+i]=0;
    p0l[i]=0; p0l[NF+i]=0; p0l[2*(size_t)NF+i]=0;
    bufA16[(size_t)i*4+2]=0; bufA16[(size_t)i*4+3]=0;
    bufB16[(size_t)i*2+1]=0;
  }
}
#define PREP_TOTAL (NLAYER*(F+F3+F+F3+11*F3+F*F+F*F3+2*F*F+F*F3+256*F) + NEDGE + NF)

// --------------------------------- fused message MLP: phi = silu(s@mw1+b1)@mw2+b2
// (only used for layer 0; layers 1,2 get phi from k_fused's tail)
__global__ __launch_bounds__(256) void k_msg(const u16* __restrict__ s_h,
                                             const u16* __restrict__ s_l,
                                             const u16* __restrict__ w1h_,  // [128][128]
                                             const u16* __restrict__ w1l_,
                                             const u16* __restrict__ w2h_,  // [384][128]
                                             const u16* __restrict__ w2l_,
                                             const float* __restrict__ b1,
                                             const float* __restrict__ b2,
                                             u16* __restrict__ bufA16,
                                             u16* __restrict__ bufB16){
  __shared__ u16 Ah[16*136], Al[16*136];
  __shared__ u16 Hh[16*136], Hl[16*136];
  __shared__ u16 Bh[64*136], Bl[64*136];
  int t = threadIdx.x, lane = t&63, w = t>>6;
  int row0 = blockIdx.x<<4;
  int l15 = lane&15, q8 = (lane>>4)<<3, qrow = (lane>>4)<<2;

  #pragma unroll
  for (int q=0;q<2;q++){
    int id = t + 256*q; int pl = id>>8, rem = id&255, r = rem>>4, c = (rem&15)<<3;
    *(uint4*)((pl?Al:Ah)+r*136+c) = *(const uint4*)((pl?s_l:s_h) + (size_t)(row0+r)*F + c);
  }

  for (int cg=0;cg<2;cg++){
    __syncthreads();
    #pragma unroll
    for (int q=0;q<8;q++){
      int id = t + 256*q; int pl = id>>10, rem = id&1023, r = rem>>4, c = (rem&15)<<3;
      *(uint4*)((pl?Bl:Bh)+r*136+c) = *(const uint4*)((pl?w1l_:w1h_) + (size_t)(cg*64+r)*F + c);
    }
    __syncthreads();
    f32x4 acc; acc[0]=0;acc[1]=0;acc[2]=0;acc[3]=0;
    #pragma unroll
    for (int k0=0;k0<F;k0+=32){
      bf16x8 a_h = *(const bf16x8*)&Ah[l15*136 + k0 + q8];
      bf16x8 a_l = *(const bf16x8*)&Al[l15*136 + k0 + q8];
      bf16x8 b_h = *(const bf16x8*)&Bh[(w*16+l15)*136 + k0 + q8];
      bf16x8 b_l = *(const bf16x8*)&Bl[(w*16+l15)*136 + k0 + q8];
      acc = __builtin_amdgcn_mfma_f32_16x16x32_bf16(a_h, b_h, acc, 0,0,0);
      acc = __builtin_amdgcn_mfma_f32_16x16x32_bf16(a_h, b_l, acc, 0,0,0);
      acc = __builtin_amdgcn_mfma_f32_16x16x32_bf16(a_l, b_h, acc, 0,0,0);
    }
    int col = cg*64 + w*16 + l15;
    float bb = b1[col];
    #pragma unroll
    for (int r=0;r<4;r++){
      float val = silu_f(acc[r] + bb);
      u16 hb = f2bf(val);
      Hh[(qrow+r)*136 + col] = hb;
      Hl[(qrow+r)*136 + col] = f2bf(val - bf2f(hb));
    }
  }

  for (int cg=0;cg<6;cg++){
    __syncthreads();
    #pragma unroll
    for (int q=0;q<8;q++){
      int id = t + 256*q; int pl = id>>10, rem = id&1023, r = rem>>4, c = (rem&15)<<3;
      *(uint4*)((pl?Bl:Bh)+r*136+c) = *(const uint4*)((pl?w2l_:w2h_) + (size_t)(cg*64+r)*F + c);
    }
    __syncthreads();
    f32x4 acc; acc[0]=0;acc[1]=0;acc[2]=0;acc[3]=0;
    #pragma unroll
    for (int k0=0;k0<F;k0+=32){
      bf16x8 a_h = *(const bf16x8*)&Hh[l15*136 + k0 + q8];
      bf16x8 a_l = *(const bf16x8*)&Hl[l15*136 + k0 + q8];
      bf16x8 b_h = *(const bf16x8*)&Bh[(w*16+l15)*136 + k0 + q8];
      bf16x8 b_l = *(const bf16x8*)&Bl[(w*16+l15)*136 + k0 + q8];
      acc = __builtin_amdgcn_mfma_f32_16x16x32_bf16(a_h, b_h, acc, 0,0,0);
      acc = __builtin_amdgcn_mfma_f32_16x16x32_bf16(a_h, b_l, acc, 0,0,0);
      acc = __builtin_amdgcn_mfma_f32_16x16x32_bf16(a_l, b_h, acc, 0,0,0);
    }
    int gc = cg*64 + w*16 + l15;
    float bb = b2[gc];
    #pragma unroll
    for (int r=0;r<4;r++){
      int grow = row0 + qrow + r;
      u16 v = f2bf(acc[r] + bb);
      size_t rowo = (size_t)grow*F;
      if (gc < F)        bufA16[(rowo + gc)*4 + 0]     = v;  // phi_vv
      else if (gc < 2*F) bufA16[(rowo + gc - F)*4 + 1] = v;  // phi_ss
      else               bufB16[(rowo + gc - 2*F)*2]   = v;  // phi_vs
    }
  }
}

// ------------------------------------------------- fused message aggregation
// 2 nodes/block (grid 4096); 2 gathers/edge, 1-deep prefetch; fdot2 W-recon.
__global__ __launch_bounds__(256) void k_agg(const uint4* __restrict__ ed_g,
                                             const uint2* __restrict__ bufA,
                                             const unsigned* __restrict__ bufB,
                                             const unsigned* __restrict__ rwp2,  // [11][3F]
                                             const u16* __restrict__ vi_h,
                                             const u16* __restrict__ vi_l,
                                             u16* __restrict__ vo_h,
                                             u16* __restrict__ vo_l,
                                             float* __restrict__ s,
                                             u16* __restrict__ s_h,
                                             u16* __restrict__ s_l){
  __shared__ uint4 ed4[128];        // 2 nodes x 16 edges x 64B
  int t = threadIdx.x;
  int half = t >> 7, f = t & 127;

  unsigned rw2[3][11];
  #pragma unroll
  for (int r2=0;r2<11;r2++){
    rw2[0][r2] = rwp2[r2*F3 + f];
    rw2[1][r2] = rwp2[r2*F3 + F + f];
    rw2[2][r2] = rwp2[r2*F3 + 2*F + f];
  }

  int nA = blockIdx.x * 2;
  if (t < 128) ed4[t] = ed_g[(size_t)nA*64 + t];
  __syncthreads();

  int n = nA + half;
  int base = half*64;
  float ds=0.f, dv0=0.f, dv1=0.f, dv2=0.f;

  int j0 = (int)(ed4[base+3].z & (N_NODES-1));
  uint2    pa = bufA[(size_t)j0*F + f];
  unsigned pb = bufB[(size_t)j0*F + f];
  for (int el=0;el<DEG;el++){
    uint2 cpa = pa; unsigned cpb = pb;
    if (el+1 < DEG){
      int j1 = (int)(ed4[base+(el+1)*4+3].z & (N_NODES-1));
      pa = bufA[(size_t)j1*F + f];
      pb = bufB[(size_t)j1*F + f];
    }
    uint4 q0 = ed4[base+el*4+0];
    uint4 q1 = ed4[base+el*4+1];
    uint4 q2 = ed4[base+el*4+2];
    uint4 q3 = ed4[base+el*4+3];
    unsigned rc[11] = {q0.x,q0.y,q0.z,q0.w, q1.x,q1.y,q1.z,q1.w, q2.x,q2.y,q2.z};
    float Wvv = 0.f, Wss = 0.f, Wvs = 0.f;
    #pragma unroll
    for (int r2=0;r2<11;r2++){
      Wvv = fdot2u(rc[r2], rw2[0][r2], Wvv);
      Wss = fdot2u(rc[r2], rw2[1][r2], Wss);
      Wvs = fdot2u(rc[r2], rw2[2][r2], Wvs);
    }
    float pvv = Wvv*lo_bf(cpa.x), pss = Wss*hi_bf(cpa.x), pvs = Wvs*lo_bf(cpb);
    ds += pss;
    dv0 += lo_bf(cpa.y)*pvv + pvs*__uint_as_float(q2.w);
    dv1 += hi_bf(cpa.y)*pvv + pvs*__uint_as_float(q3.x);
    dv2 += hi_bf(cpb)  *pvv + pvs*__uint_as_float(q3.y);
  }
  size_t i = (size_t)n*F + f;
  const float inv = 1.f/DEG;
  float sv = s[i] + ds*inv;
  s[i] = sv;
  { u16 hb = f2bf(sv); s_h[i] = hb; s_l[i] = f2bf(sv - bf2f(hb)); }
  float o0 = bf2f(vi_h[i])              + bf2f(vi_l[i])              + dv0*inv;
  float o1 = bf2f(vi_h[NF+i])           + bf2f(vi_l[NF+i])           + dv1*inv;
  float o2 = bf2f(vi_h[2*(size_t)NF+i]) + bf2f(vi_l[2*(size_t)NF+i]) + dv2*inv;
  u16 h0=f2bf(o0), h1=f2bf(o1), h2=f2bf(o2);
  vo_h[i]=h0; vo_h[NF+i]=h1; vo_h[2*(size_t)NF+i]=h2;
  vo_l[i]=f2bf(o0-bf2f(h0)); vo_l[NF+i]=f2bf(o1-bf2f(h1)); vo_l[2*(size_t)NF+i]=f2bf(o2-bf2f(h2));
}

// ---- k_fused helpers: unified weight-tile stream (all tiles are 64 x 128 u16, hi+lo)
__device__ __forceinline__ void load_tile(int idx, int t,
    const u16* uvh, const u16* uvl,
    const u16* w1h_, const u16* w1l_,
    const u16* w2h_, const u16* w2l_,
    const u16* mw1h_, const u16* mw1l_,
    const u16* mw2h_, const u16* mw2l_,
    uint4 pre[4]){
  const u16 *bh, *bl; int st, off;
  if (idx < 4){       bh=uvh;   bl=uvl;   st=128; off = idx*(64*128); }
  else if (idx < 8){  int r2=idx-4;                      // (kc outer, cgc inner)
                      bh=w1h_;  bl=w1l_;  st=256; off = (r2&1)*(64*256) + (r2>>1)*128; }
  else if (idx < 14){ bh=w2h_;  bl=w2l_;  st=128; off = (idx-8)*(64*128); }
  else if (idx < 16){ bh=mw1h_; bl=mw1l_; st=128; off = (idx-14)*(64*128); }
  else {              bh=mw2h_; bl=mw2l_; st=128; off = (idx-16)*(64*128); }
  #pragma unroll
  for (int q=0;q<4;q++){
    int id = t + 512*q; int hl = id>>10, rem = id&1023, r = rem>>4, c8 = (rem&15)<<3;
    pre[q] = *(const uint4*)((hl?bl:bh) + (size_t)off + r*st + c8);
  }
}
__device__ __forceinline__ void write_tile(u16* Bt, int t, const uint4 pre[4]){
  #pragma unroll
  for (int q=0;q<4;q++){
    int id = t + 512*q; int hl = id>>10, rem = id&1023, r = rem>>4, c8 = (rem&15)<<3;
    *(uint4*)(Bt + hl*(64*136) + r*136 + c8) = pre[q];
  }
}

// =====================================================================
// k_fused: Uv/Vv GEMM + dot/norm + update MLP + apply + next-layer msg MLP
// 32 rows/block, 512 threads (8 waves: 2 row-tiles x 4 col-waves), grid 256.
// Schedule: 1-deep register prefetch of the linear 22-tile weight stream
// (loads issue under the previous tile's MFMA) + fragment hoists.
// NOTE: __launch_bounds__(512) with NO min-waves arg — round-3's (512,2)
// capped VGPR and spilled aU/aV to scratch (VGPR 128->96, WRITE +25MB/disp).
// LDS (138KB) pins 1 block/CU anyway, so high VGPR is free here.
// =====================================================================
__global__ __launch_bounds__(512) void k_fused(
    const u16* __restrict__ uvh,  const u16* __restrict__ uvl,   // [256][128] (U rows 0..127, V rows 128..255)
    const u16* __restrict__ w1h_, const u16* __restrict__ w1l_,  // [128][256]
    const u16* __restrict__ w2h_, const u16* __restrict__ w2l_,  // [384][128]
    const float* __restrict__ b1, const float* __restrict__ b2,
    const u16* __restrict__ mw1h_, const u16* __restrict__ mw1l_, // [128][128] or null
    const u16* __restrict__ mw2h_, const u16* __restrict__ mw2l_, // [384][128]
    const float* __restrict__ mb1, const float* __restrict__ mb2,
    float* __restrict__ s, u16* __restrict__ s_h, u16* __restrict__ s_l,
    u16* __restrict__ v_h, u16* __restrict__ v_l,   // read + update in place
    u16* __restrict__ bufA16, u16* __restrict__ bufB16,
    float* __restrict__ out){
  // LDS regions (138 KB total, gfx950 has 160 KB/CU):
  __shared__ __align__(16) u16 AV [6*32*136];  // v rows, 3 comps x hi/lo   (51 KB, persists)
  __shared__ __align__(16) u16 Bt [2*64*136];  // B tile hi/lo, reused      (34 KB)
  __shared__ __align__(16) u16 AIb[2*32*264];  // ai hi/lo; later aL(half[32][392]) then mH hi/lo
  __shared__ __align__(16) u16 Hx [2*32*136];  // H hi/lo; later A_s (new-s hi/lo) for msg
  int t = threadIdx.x;
  int lane = t&63, w = t>>6;
  int qr = (w>>2)<<4;            // row-tile: 0 or 16
  int qw = w&3;                  // col-wave
  int l15 = lane&15, q8 = (lane>>4)<<3, qrow = (lane>>4)<<2;
  int row0 = blockIdx.x<<5;
  bool domsg = (mw1h_ != nullptr);
  const int NT = domsg ? 22 : 14;

  // ---- stage A: v rows (3c x hi/lo) and the s-half of ai ----
  #pragma unroll
  for (int q=0;q<6;q++){
    int id = t + 512*q;                     // 0..3071 = 6 planes x 32 x 16
    int chl = id>>9, rem = id&511, r = rem>>4, c8 = (rem&15)<<3;
    const u16* src = ((chl&1)? v_l : v_h) + (size_t)(chl>>1)*NF + (size_t)(row0+r)*F + c8;
    *(uint4*)&AV[((size_t)chl*32 + r)*136 + c8] = *(const uint4*)src;
  }
  #pragma unroll
  for (int q=0;q<2;q++){
    int id = t + 512*q;                     // 0..1023 = 2 planes x 32 x 16
    int hl = id>>9, rem = id&511, r = rem>>4, c8 = (rem&15)<<3;
    const u16* src = (hl? s_l : s_h) + (size_t)(row0+r)*F + c8;
    *(uint4*)&AIb[(size_t)hl*32*264 + r*264 + 128 + c8] = *(const uint4*)src;
  }

  uint4 pre[4];
  load_tile(0, t, uvh,uvl, w1h_,w1l_, w2h_,w2l_, mw1h_,mw1l_, mw2h_,mw2l_, pre);

  // ---- phase 1: Uv/Vv GEMM (K=128, split-bf16 hh+hl+lh) ----
  f32x4 aU[2][3], aV[2][3];
  #pragma unroll
  for (int cg=0; cg<4; cg++){               // U[0:64],U[64:128],V[0:64],V[64:128]
    __syncthreads();
    write_tile(Bt, t, pre);
    __syncthreads();
    load_tile(cg+1, t, uvh,uvl, w1h_,w1l_, w2h_,w2l_, mw1h_,mw1l_, mw2h_,mw2l_, pre);
    f32x4 acc3[3];
    #pragma unroll
    for (int c=0;c<3;c++){ acc3[c][0]=0; acc3[c][1]=0; acc3[c][2]=0; acc3[c][3]=0; }
    #pragma unroll
    for (int k0=0;k0<F;k0+=32){
      bf16x8 b_h = *(const bf16x8*)&Bt[(qw*16+l15)*136 + k0 + q8];
      bf16x8 b_l = *(const bf16x8*)&Bt[64*136 + (qw*16+l15)*136 + k0 + q8];
      #pragma unroll
      for (int c=0;c<3;c++){
        bf16x8 a_h = *(const bf16x8*)&AV[((2*c  )*32 + qr + l15)*136 + k0 + q8];
        bf16x8 a_l = *(const bf16x8*)&AV[((2*c+1)*32 + qr + l15)*136 + k0 + q8];
        acc3[c] = __builtin_amdgcn_mfma_f32_16x16x32_bf16(a_h, b_h, acc3[c], 0,0,0);
        acc3[c] = __builtin_amdgcn_mfma_f32_16x16x32_bf16(a_h, b_l, acc3[c], 0,0,0);
        acc3[c] = __builtin_amdgcn_mfma_f32_16x16x32_bf16(a_l, b_h, acc3[c], 0,0,0);
      }
    }
    #pragma unroll
    for (int c=0;c<3;c++){
      if (cg<2) aU[cg][c]=acc3[c]; else aV[cg-2][c]=acc3[c];
    }
  }

  // ---- dot / norm in-register; norm -> ai[:,0:128] ----
  f32x4 dotf[2];
  #pragma unroll
  for (int g=0; g<2; g++){
    #pragma unroll
    for (int r=0;r<4;r++){
      float d=0.f, n2=0.f;
      #pragma unroll
      for (int c=0;c<3;c++){ d += aU[g][c][r]*aV[g][c][r]; n2 += aV[g][c][r]*aV[g][c][r]; }
      dotf[g][r]=d;
      int row = qr+qrow+r, col = g*64+qw*16+l15;
      float vn = sqrtf(n2);
      u16 h = f2bf(vn);
      AIb[row*264+col] = h;
      AIb[32*264 + row*264+col] = f2bf(vn - bf2f(h));
    }
  }
  __syncthreads();                           // norm writes visible

  // ---- phase 2: H = silu(ai @ w1 + b1)   (K=256; kc outer, cgc inner) ----
  f32x4 acc2[2];
  acc2[0][0]=0;acc2[0][1]=0;acc2[0][2]=0;acc2[0][3]=0; acc2[1]=acc2[0];
  #pragma unroll
  for (int kc=0; kc<2; kc++){
    bf16x8 a2h[4], a2l[4];                   // A-fragments reused for both cgc tiles
    #pragma unroll
    for (int ks=0; ks<4; ks++){
      a2h[ks] = *(const bf16x8*)&AIb[(qr+l15)*264 + kc*128 + ks*32 + q8];
      a2l[ks] = *(const bf16x8*)&AIb[32*264 + (qr+l15)*264 + kc*128 + ks*32 + q8];
    }
    #pragma unroll
    for (int cgc=0; cgc<2; cgc++){
      int tix = 4 + kc*2 + cgc;
      __syncthreads();
      write_tile(Bt, t, pre);
      __syncthreads();
      load_tile(tix+1, t, uvh,uvl, w1h_,w1l_, w2h_,w2l_, mw1h_,mw1l_, mw2h_,mw2l_, pre);
      #pragma unroll
      for (int ks=0; ks<4; ks++){
        bf16x8 b_h = *(const bf16x8*)&Bt[(qw*16+l15)*136 + ks*32 + q8];
        bf16x8 b_l = *(const bf16x8*)&Bt[64*136 + (qw*16+l15)*136 + ks*32 + q8];
        acc2[cgc] = __builtin_amdgcn_mfma_f32_16x16x32_bf16(a2h[ks], b_h, acc2[cgc], 0,0,0);
        acc2[cgc] = __builtin_amdgcn_mfma_f32_16x16x32_bf16(a2h[ks], b_l, acc2[cgc], 0,0,0);
        acc2[cgc] = __builtin_amdgcn_mfma_f32_16x16x32_bf16(a2l[ks], b_h, acc2[cgc], 0,0,0);
      }
    }
  }
  #pragma unroll
  for (int cgc=0; cgc<2; cgc++){
    int col = cgc*64 + qw*16 + l15;
    float bb = b1[col];
    #pragma unroll
    for (int r=0;r<4;r++){
      float val = silu_f(acc2[cgc][r] + bb);
      u16 hb = f2bf(val);
      Hx[(qr+qrow+r)*136 + col] = hb;
      Hx[32*136 + (qr+qrow+r)*136 + col] = f2bf(val - bf2f(hb));
    }
  }
  __syncthreads();                           // H visible

  // ---- phase 3: a = H @ w2 + b2 -> aL (half, aliases ai region) ----
  bf16x8 hah[4], hal[4];                     // hoisted A-fragments (same for all 6 tiles)
  #pragma unroll
  for (int ks=0; ks<4; ks++){
    hah[ks] = *(const bf16x8*)&Hx[(qr+l15)*136 + ks*32 + q8];
    hal[ks] = *(const bf16x8*)&Hx[32*136 + (qr+l15)*136 + ks*32 + q8];
  }
  __half* aL = (__half*)AIb;                 // [32][392]; ai reads are done
  #pragma unroll
  for (int cg=0; cg<6; cg++){
    int tix = 8 + cg;
    __syncthreads();
    write_tile(Bt, t, pre);
    __syncthreads();
    if (tix+1 < NT)
      load_tile(tix+1, t, uvh,uvl, w1h_,w1l_, w2h_,w2l_, mw1h_,mw1l_, mw2h_,mw2l_, pre);
    f32x4 acc; acc[0]=0;acc[1]=0;acc[2]=0;acc[3]=0;
    #pragma unroll
    for (int ks=0; ks<4; ks++){
      bf16x8 b_h = *(const bf16x8*)&Bt[(qw*16+l15)*136 + ks*32 + q8];
      bf16x8 b_l = *(const bf16x8*)&Bt[64*136 + (qw*16+l15)*136 + ks*32 + q8];
      acc = __builtin_amdgcn_mfma_f32_16x16x32_bf16(hah[ks], b_h, acc, 0,0,0);
      acc = __builtin_amdgcn_mfma_f32_16x16x32_bf16(hah[ks], b_l, acc, 0,0,0);
      acc = __builtin_amdgcn_mfma_f32_16x16x32_bf16(hal[ks], b_h, acc, 0,0,0);
    }
    int gc = cg*64 + qw*16 + l15;
    float bb = b2[gc];
    #pragma unroll
    for (int r=0;r<4;r++)
      aL[(qr+qrow+r)*392 + gc] = __float2half(acc[r] + bb);
  }
  __syncthreads();

  // ---- epilogue in fragment layout: s,v update + bufA/B v-packs + A_s for msg ----
  #pragma unroll
  for (int g=0; g<2; g++){
    #pragma unroll
    for (int r=0; r<4; r++){
      int row = qr+qrow+r;
      int col = g*64+qw*16+l15;
      int grow = row0+row;
      size_t i = (size_t)grow*F + col;
      float avv = __half2float(aL[row*392 + col]);
      float asv = __half2float(aL[row*392 + F + col]);
      float ass = __half2float(aL[row*392 + 2*F + col]);
      float sv = s[i] + ass + asv*dotf[g][r];
      s[i] = sv;
      u16 hb = f2bf(sv); u16 lb = f2bf(sv - bf2f(hb));
      s_h[i]=hb; s_l[i]=lb;
      float nv[3];
      #pragma unroll
      for (int c=0;c<3;c++){
        float vold = bf2f(AV[((2*c)*32+row)*136+col]) + bf2f(AV[((2*c+1)*32+row)*136+col]);
        nv[c] = vold + aU[g][c][r]*avv;
      }
      u16 h0=f2bf(nv[0]), h1=f2bf(nv[1]), h2=f2bf(nv[2]);
      v_h[i]=h0; v_h[NF+i]=h1; v_h[2*(size_t)NF+i]=h2;
      v_l[i]=f2bf(nv[0]-bf2f(h0)); v_l[NF+i]=f2bf(nv[1]-bf2f(h1)); v_l[2*(size_t)NF+i]=f2bf(nv[2]-bf2f(h2));
      bufA16[i*4+2]=h0; bufA16[i*4+3]=h1; bufB16[i*2+1]=h2;
      if (out){
        out[i] = sv;
        out[NF + i*3 + 0] = nv[0];
        out[NF + i*3 + 1] = nv[1];
        out[NF + i*3 + 2] = nv[2];
      }
      if (domsg){                                  // A_s aliases Hx (H reads done)
        Hx[row*136+col] = hb;
        Hx[32*136 + row*136+col] = lb;
      }
    }
  }

  // ---- phase 4 (layers 0,1): next layer's msg MLP, phi -> bufA/bufB ----
  if (domsg){
    __syncthreads();                         // A_s visible (also: all aL reads done)
    // mH = silu(new_s @ mw1 + mb1)  (K=128); mH aliases AIb
    bf16x8 sah[4], sal[4];
    #pragma unroll
    for (int ks=0; ks<4; ks++){
      sah[ks] = *(const bf16x8*)&Hx[(qr+l15)*136 + ks*32 + q8];
      sal[ks] = *(const bf16x8*)&Hx[32*136 + (qr+l15)*136 + ks*32 + q8];
    }
    f32x4 acc4[2];
    acc4[0][0]=0;acc4[0][1]=0;acc4[0][2]=0;acc4[0][3]=0; acc4[1]=acc4[0];
    #pragma unroll
    for (int cgc=0; cgc<2; cgc++){
      int tix = 14 + cgc;
      __syncthreads();
      write_tile(Bt, t, pre);
      __syncthreads();
      load_tile(tix+1, t, uvh,uvl, w1h_,w1l_, w2h_,w2l_, mw1h_,mw1l_, mw2h_,mw2l_, pre);
      #pragma unroll
      for (int ks=0; ks<4; ks++){
        bf16x8 b_h = *(const bf16x8*)&Bt[(qw*16+l15)*136 + ks*32 + q8];
        bf16x8 b_l = *(const bf16x8*)&Bt[64*136 + (qw*16+l15)*136 + ks*32 + q8];
        acc4[cgc] = __builtin_amdgcn_mfma_f32_16x16x32_bf16(sah[ks], b_h, acc4[cgc], 0,0,0);
        acc4[cgc] = __builtin_amdgcn_mfma_f32_16x16x32_bf16(sah[ks], b_l, acc4[cgc], 0,0,0);
        acc4[cgc] = __builtin_amdgcn_mfma_f32_16x16x32_bf16(sal[ks], b_h, acc4[cgc], 0,0,0);
      }
    }
    #pragma unroll
    for (int cgc=0; cgc<2; cgc++){
      int col = cgc*64 + qw*16 + l15;
      float bb = mb1[col];
      #pragma unroll
      for (int r=0;r<4;r++){
        float val = silu_f(acc4[cgc][r] + bb);
        u16 hb = f2bf(val);
        AIb[(qr+qrow+r)*136 + col] = hb;                  // mH hi (stride 136)
        AIb[32*136 + (qr+qrow+r)*136 + col] = f2bf(val - bf2f(hb));
      }
    }
    __syncthreads();                         // mH visible

    // phi = mH @ mw2 + mb2 -> bufA/bufB
    bf16x8 mhh[4], mhl[4];
    #pragma unroll
    for (int ks=0; ks<4; ks++){
      mhh[ks] = *(const bf16x8*)&AIb[(qr+l15)*136 + ks*32 + q8];
      mhl[ks] = *(const bf16x8*)&AIb[32*136 + (qr+l15)*136 + ks*32 + q8];
    }
    #pragma unroll
    for (int cg=0; cg<6; cg++){
      int tix = 16 + cg;
      __syncthreads();
      write_tile(Bt, t, pre);
      __syncthreads();
      if (tix+1 < NT)
        load_tile(tix+1, t, uvh,uvl, w1h_,w1l_, w2h_,w2l_, mw1h_,mw1l_, mw2h_,mw2l_, pre);
      f32x4 acc; acc[0]=0;acc[1]=0;acc[2]=0;acc[3]=0;
      #pragma unroll
      for (int ks=0; ks<4; ks++){
        bf16x8 b_h = *(const bf16x8*)&Bt[(qw*16+l15)*136 + ks*32 + q8];
        bf16x8 b_l = *(const bf16x8*)&Bt[64*136 + (qw*16+l15)*136 + ks*32 + q8];
        acc = __builtin_amdgcn_mfma_f32_16x16x32_bf16(mhh[ks], b_h, acc, 0,0,0);
        acc = __builtin_amdgcn_mfma_f32_16x16x32_bf16(mhh[ks], b_l, acc, 0,0,0);
        acc = __builtin_amdgcn_mfma_f32_16x16x32_bf16(mhl[ks], b_h, acc, 0,0,0);
      }
      int gc = cg*64 + qw*16 + l15;
      float bb = mb2[gc];
      #pragma unroll
      for (int r=0;r<4;r++){
        int grow = row0 + qr + qrow + r;
        u16 v16 = f2bf(acc[r] + bb);
        size_t rowo = (size_t)grow*F;
        if (gc < F)        bufA16[(rowo + gc)*4 + 0]     = v16;  // phi_vv
        else if (gc < 2*F) bufA16[(rowo + gc - F)*4 + 1] = v16;  // phi_ss
        else               bufB16[(rowo + gc - 2*F)*2]   = v16;  // phi_vs
      }
    }
  }
}

// ------------------------------------------------------------------ launch
extern "C" void kernel_launch(void* const* d_in, const int* in_sizes, int n_in,
                              void* d_out, int out_size, void* d_ws, size_t ws_size,
                              hipStream_t stream) {
  const int* atoms   = (const int*)d_in[0];
  const int* idxj    = (const int*)d_in[2];

  float* W = (float*)d_ws;
  size_t off = 64;
  int* flag = (int*)d_ws;
  #define ALLOCF(name, cnt) float* name = W+off; off += (((cnt)+63)&~(size_t)63)
  #define ALLOCU(name, cnt) u16* name = (u16*)(W+off); off += ((((cnt)+1)/2+63)&~(size_t)63)
  ALLOCF(c_mb1, NLAYER*F);
  ALLOCF(c_mb2, NLAYER*F3);
  ALLOCF(c_b1,  NLAYER*F);
  ALLOCF(c_b2,  NLAYER*F3);
  unsigned* c_rwp2 = (unsigned*)(W+off); off += ((NLAYER*11*F3+63)&~(size_t)63);
  uint4* edata = (uint4*)(W+off); off += (size_t)NEDGE*16;  // E x 64B = E*16 floats
  ALLOCU(w_mw1h, NLAYER*F*F);   ALLOCU(w_mw1l, NLAYER*F*F);
  ALLOCU(w_mw2h, NLAYER*F*F3);  ALLOCU(w_mw2l, NLAYER*F*F3);
  ALLOCU(w_uvh,  NLAYER*256*F); ALLOCU(w_uvl,  NLAYER*256*F);
  ALLOCU(w_w1h,  NLAYER*F*256); ALLOCU(w_w1l,  NLAYER*F*256);
  ALLOCU(w_w2h,  NLAYER*F*F3);  ALLOCU(w_w2l,  NLAYER*F*F3);
  uint2* bufA = (uint2*)(W+off); off += (size_t)2*NF;       // NF x 8B
  unsigned* bufB = (unsigned*)(W+off); off += (size_t)NF;   // NF x 4B
  ALLOCU(p0h, (size_t)3*NF); ALLOCU(p0l, (size_t)3*NF);
  ALLOCU(p1h, (size_t)3*NF); ALLOCU(p1l, (size_t)3*NF);
  ALLOCU(s_h,  NF); ALLOCU(s_l,  NF);
  ALLOCF(s,    NF);

  k_detect<<<1, 64, 0, stream>>>((const u16*)d_in[4], flag);
  k_prep<<<(PREP_TOTAL+255)/256, 256, 0, stream>>>(
      d_in[7], d_in[9], d_in[15], d_in[17],
      d_in[10], d_in[11],
      d_in[6], d_in[8], d_in[14], d_in[16],
      d_in[12], d_in[13],
      d_in[4], d_in[3], idxj,
      atoms, d_in[5],
      c_mb1, c_mb2, c_b1, c_b2, c_rwp2,
      w_mw1h, w_mw1l, w_mw2h, w_mw2l, w_w1h, w_w1l,
      w_w2h, w_w2l, w_uvh, w_uvl, edata,
      s, s_h, s_l, p0h, p0l, (u16*)bufA, (u16*)bufB, flag);

  // layer-0 message MLP (later layers get phi from k_fused's tail)
  k_msg<<<N_NODES/16, 256, 0, stream>>>(
      s_h, s_l,
      w_mw1h, w_mw1l, w_mw2h, w_mw2l,
      c_mb1, c_mb2,
      (u16*)bufA, (u16*)bufB);

  for (int l=0; l<NLAYER; l++){
    u16* vih = (l & 1) ? p1h : p0h;
    u16* vil = (l & 1) ? p1l : p0l;
    u16* voh = (l & 1) ? p0h : p1h;
    u16* vol = (l & 1) ? p0l : p1l;
    k_agg<<<N_NODES/2, 256, 0, stream>>>(
        edata, bufA, bufB, c_rwp2 + (size_t)l*11*F3,
        vih, vil, voh, vol, s, s_h, s_l);
    int ln = l + 1;
    int domsg = (l < NLAYER-1);
    k_fused<<<N_NODES/32, 512, 0, stream>>>(
        w_uvh + (size_t)l*256*F, w_uvl + (size_t)l*256*F,
        w_w1h + (size_t)l*F*256, w_w1l + (size_t)l*F*256,
        w_w2h + (size_t)l*F*F3,  w_w2l + (size_t)l*F*F3,
        c_b1 + (size_t)l*F, c_b2 + (size_t)l*F3,
        domsg ? w_mw1h + (size_t)ln*F*F  : nullptr,
        domsg ? w_mw1l + (size_t)ln*F*F  : nullptr,
        domsg ? w_mw2h + (size_t)ln*F*F3 : nullptr,
        domsg ? w_mw2l + (size_t)ln*F*F3 : nullptr,
        domsg ? c_mb1 + (size_t)ln*F  : nullptr,
        domsg ? c_mb2 + (size_t)ln*F3 : nullptr,
        s, s_h, s_l, voh, vol,
        (u16*)bufA, (u16*)bufB,
        (l == NLAYER-1) ? (float*)d_out : nullptr);
  }
}

// Round 5
// 319.196 us; speedup vs baseline: 1.2868x; 1.2868x over previous
//
#include <hip/hip_runtime.h>
#include <hip/hip_fp16.h>

#define N_NODES 8192
#define DEG     16
#define NEDGE   (N_NODES*DEG)
#define F       128
#define F3      384
#define RBF     20
#define NLAYER  3
#define NF      (N_NODES*F)
#define PI_F    3.14159265358979f

typedef unsigned short u16;
typedef __bf16 bf16x8 __attribute__((ext_vector_type(8)));
typedef float  f32x4  __attribute__((ext_vector_type(4)));
typedef _Float16 f16x2 __attribute__((ext_vector_type(2)));

__device__ __forceinline__ float bf2f(u16 u){ return __uint_as_float(((unsigned)u)<<16); }
__device__ __forceinline__ u16 f2bf(float f){
  unsigned x = __float_as_uint(f);
  unsigned r = (x + 0x7FFFu + ((x>>16)&1u)) >> 16;   // RNE
  return (u16)r;
}
__device__ __forceinline__ float lo_bf(unsigned u){ return __uint_as_float(u<<16); }
__device__ __forceinline__ float hi_bf(unsigned u){ return __uint_as_float(u & 0xFFFF0000u); }
__device__ __forceinline__ float silu_f(float x){ return x / (1.f + __expf(-x)); }
__device__ __forceinline__ float ldsrc(const void* src, int i, int bf){
  return bf ? bf2f(((const u16*)src)[i]) : ((const float*)src)[i];
}
__device__ __forceinline__ unsigned packh2(float a, float b){
  return (unsigned)__half_as_ushort(__float2half(a)) |
         ((unsigned)__half_as_ushort(__float2half(b)) << 16);
}
// v_dot2_f32_f16: c += a.x*b.x + a.y*b.y  (fp32 accumulate, 1 VALU op)
__device__ __forceinline__ float fdot2u(unsigned a, unsigned b, float c){
  return __builtin_amdgcn_fdot2(__builtin_bit_cast(f16x2, a),
                                __builtin_bit_cast(f16x2, b), c, false);
}

// ------------------------------------------------------------ dtype detect
__global__ void k_detect(const u16* __restrict__ rd, int* __restrict__ flag){
  if (threadIdx.x == 0 && blockIdx.x == 0){
    int ok = 1;
    for (int i = 0; i < 128; i++){
      float v = bf2f(rd[2*i]);
      if (!(v > 0.01f && v < 4.0f)) { ok = 0; break; }
    }
    *flag = ok;   // 1 = inputs bf16, 0 = fp32
  }
}

// ------------------------------------------- split helper: [L][K][N] -> [L][N][K] hi/lo
__device__ __forceinline__ void splitw(const void* src, u16* bh, u16* bl,
                                       int i, int K, int Ncol, int bf){
  int kn = K*Ncol; int l = i/kn; int r = i - l*kn; int k = r/Ncol; int n = r - k*Ncol;
  float w = ldsrc(src, i, bf);
  u16 h = f2bf(w);
  size_t o = (size_t)l*kn + (size_t)n*K + k;
  bh[o] = h; bl[o] = f2bf(w - bf2f(h));
}

// -------------------------------------- fused preamble (weights + edges + node init)
__global__ __launch_bounds__(256) void k_prep(
    const void* mb1, const void* mb2, const void* b1, const void* b2,
    const void* rw,  const void* rb,
    const void* mw1, const void* mw2, const void* w1, const void* w2,
    const void* Uw,  const void* Vw,
    const void* dist, const void* dirv, const int* __restrict__ idxj,
    const int* __restrict__ atoms, const void* __restrict__ emb,
    float* c_mb1, float* c_mb2, float* c_b1, float* c_b2,
    unsigned* rwp2,                 // [L][11][3F]
    u16* mw1h, u16* mw1l, u16* mw2h, u16* mw2l, u16* w1h, u16* w1l,
    u16* w2h, u16* w2l, u16* uvh, u16* uvl,
    uint4* edata,                   // [E][4]
    float* s, u16* s_h, u16* s_l,
    u16* p0h, u16* p0l, u16* bufA16, u16* bufB16,
    const int* __restrict__ flag){
  int i = blockIdx.x*256 + threadIdx.x;
  int bf = *flag;
  const int S0=NLAYER*F, S1=NLAYER*F3, S2=NLAYER*F, S3=NLAYER*F3;
  const int S4=NLAYER*11*F3;
  const int S5=NLAYER*F*F, S6=NLAYER*F*F3, S7=NLAYER*2*F*F, S8=NLAYER*F*F3, S9=NLAYER*256*F;
  if (i < S0){ c_mb1[i]=ldsrc(mb1,i,bf); return; } i-=S0;
  if (i < S1){ c_mb2[i]=ldsrc(mb2,i,bf); return; } i-=S1;
  if (i < S2){ c_b1[i] =ldsrc(b1, i,bf); return; } i-=S2;
  if (i < S3){ c_b2[i] =ldsrc(b2, i,bf); return; } i-=S3;
  if (i < S4){
    int l = i/(11*F3); int r = i - l*(11*F3); int r2 = r/F3; int col = r - r2*F3;
    float w0, w1v;
    if (r2 < 10){
      w0  = ldsrc(rw, (l*RBF + 2*r2  )*F3 + col, bf);
      w1v = ldsrc(rw, (l*RBF + 2*r2+1)*F3 + col, bf);
    } else {
      w0  = ldsrc(rb, l*F3 + col, bf);
      w1v = 0.f;
    }
    rwp2[i] = packh2(w0, w1v);
    return;
  } i-=S4;
  if (i < S5){ splitw(mw1, mw1h, mw1l, i, F,   F,  bf); return; } i-=S5;
  if (i < S6){ splitw(mw2, mw2h, mw2l, i, F,   F3, bf); return; } i-=S6;
  if (i < S7){ splitw(w1,  w1h,  w1l,  i, 2*F, F,  bf); return; } i-=S7;
  if (i < S8){ splitw(w2,  w2h,  w2l,  i, F,   F3, bf); return; } i-=S8;
  if (i < S9){
    int l=i/(256*F); int r=i-l*(256*F); int n=r>>7; int k=r&127;
    int si=(l*F+k)*F+(n&127);
    float w = ldsrc((n<128)?Uw:Vw, si, bf);
    u16 h=f2bf(w); uvh[i]=h; uvl[i]=f2bf(w-bf2f(h));
    return;
  } i-=S9;
  if (i < NEDGE){
    int e = i;
    float d = ldsrc(dist, e, bf);
    float th = PI_F*d*(1.f/3.f);
    float c  = __cosf(th);
    float s1 = __sinf(th);
    float cut = 0.5f*(c + 1.0f);
    float ic = cut/d;
    // Chebyshev recurrence: sin((k+1)th) = 2c*sin(k th) - sin((k-1) th)
    float sk[RBF+1];
    sk[0] = s1; float sm1 = 0.f, s0 = s1;
    #pragma unroll
    for (int k=1;k<=RBF;k++){ float sn = 2.f*c*s0 - sm1; sk[k-1] = s0; sm1 = s0; s0 = sn; }
    unsigned o[16];
    #pragma unroll
    for (int r2=0;r2<10;r2++)
      o[r2] = packh2(sk[2*r2]*ic, sk[2*r2+1]*ic);
    o[10] = packh2(cut, 0.f);
    o[11] = __float_as_uint(ldsrc(dirv, e*3+0, bf));
    o[12] = __float_as_uint(ldsrc(dirv, e*3+1, bf));
    o[13] = __float_as_uint(ldsrc(dirv, e*3+2, bf));
    o[14] = (unsigned)idxj[e];
    o[15] = 0;
    uint4* dst = edata + (size_t)e*4;
    dst[0] = make_uint4(o[0],o[1],o[2],o[3]);
    dst[1] = make_uint4(o[4],o[5],o[6],o[7]);
    dst[2] = make_uint4(o[8],o[9],o[10],o[11]);
    dst[3] = make_uint4(o[12],o[13],o[14],o[15]);
    return;
  } i-=NEDGE;
  if (i < NF){                      // node init
    int n = i >> 7, f = i & 127;
    float sv = ldsrc(emb, atoms[n]*F + f, bf);
    s[i] = sv;
    u16 hb = f2bf(sv); s_h[i] = hb; s_l[i] = f2bf(sv - bf2f(hb));
    p0h[i]=0; p0h[NF+i]=0; p0h[2*(size_t)NF+i]=0;
    p0l[i]=0; p0l[NF+i]=0; p0l[2*(size_t)NF+i]=0;
    bufA16[(size_t)i*4+2]=0; bufA16[(size_t)i*4+3]=0;
    bufB16[(size_t)i*2+1]=0;
  }
}
#define PREP_TOTAL (NLAYER*(F+F3+F+F3+11*F3+F*F+F*F3+2*F*F+F*F3+256*F) + NEDGE + NF)

// --------------------------------- fused message MLP: phi = silu(s@mw1+b1)@mw2+b2
// (only used for layer 0; layers 1,2 get phi from k_fused's tail)
__global__ __launch_bounds__(256) void k_msg(const u16* __restrict__ s_h,
                                             const u16* __restrict__ s_l,
                                             const u16* __restrict__ w1h_,  // [128][128]
                                             const u16* __restrict__ w1l_,
                                             const u16* __restrict__ w2h_,  // [384][128]
                                             const u16* __restrict__ w2l_,
                                             const float* __restrict__ b1,
                                             const float* __restrict__ b2,
                                             u16* __restrict__ bufA16,
                                             u16* __restrict__ bufB16){
  __shared__ u16 Ah[16*136], Al[16*136];
  __shared__ u16 Hh[16*136], Hl[16*136];
  __shared__ u16 Bh[64*136], Bl[64*136];
  int t = threadIdx.x, lane = t&63, w = t>>6;
  int row0 = blockIdx.x<<4;
  int l15 = lane&15, q8 = (lane>>4)<<3, qrow = (lane>>4)<<2;

  #pragma unroll
  for (int q=0;q<2;q++){
    int id = t + 256*q; int pl = id>>8, rem = id&255, r = rem>>4, c = (rem&15)<<3;
    *(uint4*)((pl?Al:Ah)+r*136+c) = *(const uint4*)((pl?s_l:s_h) + (size_t)(row0+r)*F + c);
  }

  for (int cg=0;cg<2;cg++){
    __syncthreads();
    #pragma unroll
    for (int q=0;q<8;q++){
      int id = t + 256*q; int pl = id>>10, rem = id&1023, r = rem>>4, c = (rem&15)<<3;
      *(uint4*)((pl?Bl:Bh)+r*136+c) = *(const uint4*)((pl?w1l_:w1h_) + (size_t)(cg*64+r)*F + c);
    }
    __syncthreads();
    f32x4 acc; acc[0]=0;acc[1]=0;acc[2]=0;acc[3]=0;
    #pragma unroll
    for (int k0=0;k0<F;k0+=32){
      bf16x8 a_h = *(const bf16x8*)&Ah[l15*136 + k0 + q8];
      bf16x8 a_l = *(const bf16x8*)&Al[l15*136 + k0 + q8];
      bf16x8 b_h = *(const bf16x8*)&Bh[(w*16+l15)*136 + k0 + q8];
      bf16x8 b_l = *(const bf16x8*)&Bl[(w*16+l15)*136 + k0 + q8];
      acc = __builtin_amdgcn_mfma_f32_16x16x32_bf16(a_h, b_h, acc, 0,0,0);
      acc = __builtin_amdgcn_mfma_f32_16x16x32_bf16(a_h, b_l, acc, 0,0,0);
      acc = __builtin_amdgcn_mfma_f32_16x16x32_bf16(a_l, b_h, acc, 0,0,0);
    }
    int col = cg*64 + w*16 + l15;
    float bb = b1[col];
    #pragma unroll
    for (int r=0;r<4;r++){
      float val = silu_f(acc[r] + bb);
      u16 hb = f2bf(val);
      Hh[(qrow+r)*136 + col] = hb;
      Hl[(qrow+r)*136 + col] = f2bf(val - bf2f(hb));
    }
  }

  for (int cg=0;cg<6;cg++){
    __syncthreads();
    #pragma unroll
    for (int q=0;q<8;q++){
      int id = t + 256*q; int pl = id>>10, rem = id&1023, r = rem>>4, c = (rem&15)<<3;
      *(uint4*)((pl?Bl:Bh)+r*136+c) = *(const uint4*)((pl?w2l_:w2h_) + (size_t)(cg*64+r)*F + c);
    }
    __syncthreads();
    f32x4 acc; acc[0]=0;acc[1]=0;acc[2]=0;acc[3]=0;
    #pragma unroll
    for (int k0=0;k0<F;k0+=32){
      bf16x8 a_h = *(const bf16x8*)&Hh[l15*136 + k0 + q8];
      bf16x8 a_l = *(const bf16x8*)&Hl[l15*136 + k0 + q8];
      bf16x8 b_h = *(const bf16x8*)&Bh[(w*16+l15)*136 + k0 + q8];
      bf16x8 b_l = *(const bf16x8*)&Bl[(w*16+l15)*136 + k0 + q8];
      acc = __builtin_amdgcn_mfma_f32_16x16x32_bf16(a_h, b_h, acc, 0,0,0);
      acc = __builtin_amdgcn_mfma_f32_16x16x32_bf16(a_h, b_l, acc, 0,0,0);
      acc = __builtin_amdgcn_mfma_f32_16x16x32_bf16(a_l, b_h, acc, 0,0,0);
    }
    int gc = cg*64 + w*16 + l15;
    float bb = b2[gc];
    #pragma unroll
    for (int r=0;r<4;r++){
      int grow = row0 + qrow + r;
      u16 v = f2bf(acc[r] + bb);
      size_t rowo = (size_t)grow*F;
      if (gc < F)        bufA16[(rowo + gc)*4 + 0]     = v;  // phi_vv
      else if (gc < 2*F) bufA16[(rowo + gc - F)*4 + 1] = v;  // phi_ss
      else               bufB16[(rowo + gc - 2*F)*2]   = v;  // phi_vs
    }
  }
}

// ------------------------------------------------- fused message aggregation
// 2 nodes/block (grid 4096); 2 gathers/edge, 1-deep prefetch; fdot2 W-recon.
__global__ __launch_bounds__(256) void k_agg(const uint4* __restrict__ ed_g,
                                             const uint2* __restrict__ bufA,
                                             const unsigned* __restrict__ bufB,
                                             const unsigned* __restrict__ rwp2,  // [11][3F]
                                             const u16* __restrict__ vi_h,
                                             const u16* __restrict__ vi_l,
                                             u16* __restrict__ vo_h,
                                             u16* __restrict__ vo_l,
                                             float* __restrict__ s,
                                             u16* __restrict__ s_h,
                                             u16* __restrict__ s_l){
  __shared__ uint4 ed4[128];        // 2 nodes x 16 edges x 64B
  int t = threadIdx.x;
  int half = t >> 7, f = t & 127;

  unsigned rw2[3][11];
  #pragma unroll
  for (int r2=0;r2<11;r2++){
    rw2[0][r2] = rwp2[r2*F3 + f];
    rw2[1][r2] = rwp2[r2*F3 + F + f];
    rw2[2][r2] = rwp2[r2*F3 + 2*F + f];
  }

  int nA = blockIdx.x * 2;
  if (t < 128) ed4[t] = ed_g[(size_t)nA*64 + t];
  __syncthreads();

  int n = nA + half;
  int base = half*64;
  float ds=0.f, dv0=0.f, dv1=0.f, dv2=0.f;

  int j0 = (int)(ed4[base+3].z & (N_NODES-1));
  uint2    pa = bufA[(size_t)j0*F + f];
  unsigned pb = bufB[(size_t)j0*F + f];
  for (int el=0;el<DEG;el++){
    uint2 cpa = pa; unsigned cpb = pb;
    if (el+1 < DEG){
      int j1 = (int)(ed4[base+(el+1)*4+3].z & (N_NODES-1));
      pa = bufA[(size_t)j1*F + f];
      pb = bufB[(size_t)j1*F + f];
    }
    uint4 q0 = ed4[base+el*4+0];
    uint4 q1 = ed4[base+el*4+1];
    uint4 q2 = ed4[base+el*4+2];
    uint4 q3 = ed4[base+el*4+3];
    unsigned rc[11] = {q0.x,q0.y,q0.z,q0.w, q1.x,q1.y,q1.z,q1.w, q2.x,q2.y,q2.z};
    float Wvv = 0.f, Wss = 0.f, Wvs = 0.f;
    #pragma unroll
    for (int r2=0;r2<11;r2++){
      Wvv = fdot2u(rc[r2], rw2[0][r2], Wvv);
      Wss = fdot2u(rc[r2], rw2[1][r2], Wss);
      Wvs = fdot2u(rc[r2], rw2[2][r2], Wvs);
    }
    float pvv = Wvv*lo_bf(cpa.x), pss = Wss*hi_bf(cpa.x), pvs = Wvs*lo_bf(cpb);
    ds += pss;
    dv0 += lo_bf(cpa.y)*pvv + pvs*__uint_as_float(q2.w);
    dv1 += hi_bf(cpa.y)*pvv + pvs*__uint_as_float(q3.x);
    dv2 += hi_bf(cpb)  *pvv + pvs*__uint_as_float(q3.y);
  }
  size_t i = (size_t)n*F + f;
  const float inv = 1.f/DEG;
  float sv = s[i] + ds*inv;
  s[i] = sv;
  { u16 hb = f2bf(sv); s_h[i] = hb; s_l[i] = f2bf(sv - bf2f(hb)); }
  float o0 = bf2f(vi_h[i])              + bf2f(vi_l[i])              + dv0*inv;
  float o1 = bf2f(vi_h[NF+i])           + bf2f(vi_l[NF+i])           + dv1*inv;
  float o2 = bf2f(vi_h[2*(size_t)NF+i]) + bf2f(vi_l[2*(size_t)NF+i]) + dv2*inv;
  u16 h0=f2bf(o0), h1=f2bf(o1), h2=f2bf(o2);
  vo_h[i]=h0; vo_h[NF+i]=h1; vo_h[2*(size_t)NF+i]=h2;
  vo_l[i]=f2bf(o0-bf2f(h0)); vo_l[NF+i]=f2bf(o1-bf2f(h1)); vo_l[2*(size_t)NF+i]=f2bf(o2-bf2f(h2));
}

// ---- k_fused helpers: unified weight-tile stream (all tiles are 64 x 128 u16, hi+lo)
// Pre4 is a STRUCT BY VALUE (named fields, no array, no pointer out-param):
// round-3/4's `uint4 pre[4]` by-pointer failed alloca promotion -> scratch
// (VGPR 96 + 25MB/dispatch spill writes, invariant to launch bounds).
struct Pre4 { uint4 v0, v1, v2, v3; };

__device__ __forceinline__ Pre4 load_tile(int idx, int t,
    const u16* uvh, const u16* uvl,
    const u16* w1h_, const u16* w1l_,
    const u16* w2h_, const u16* w2l_,
    const u16* mw1h_, const u16* mw1l_,
    const u16* mw2h_, const u16* mw2l_){
  const u16 *bh, *bl; int st, off;
  if (idx < 4){       bh=uvh;   bl=uvl;   st=128; off = idx*(64*128); }
  else if (idx < 8){  int r2=idx-4;                      // (kc outer, cgc inner)
                      bh=w1h_;  bl=w1l_;  st=256; off = (r2&1)*(64*256) + (r2>>1)*128; }
  else if (idx < 14){ bh=w2h_;  bl=w2l_;  st=128; off = (idx-8)*(64*128); }
  else if (idx < 16){ bh=mw1h_; bl=mw1l_; st=128; off = (idx-14)*(64*128); }
  else {              bh=mw2h_; bl=mw2l_; st=128; off = (idx-16)*(64*128); }
  Pre4 p;
  { int id=t;      int hl=id>>10, rem=id&1023, r=rem>>4, c8=(rem&15)<<3;
    p.v0 = *(const uint4*)((hl?bl:bh) + (size_t)off + r*st + c8); }
  { int id=t+512;  int hl=id>>10, rem=id&1023, r=rem>>4, c8=(rem&15)<<3;
    p.v1 = *(const uint4*)((hl?bl:bh) + (size_t)off + r*st + c8); }
  { int id=t+1024; int hl=id>>10, rem=id&1023, r=rem>>4, c8=(rem&15)<<3;
    p.v2 = *(const uint4*)((hl?bl:bh) + (size_t)off + r*st + c8); }
  { int id=t+1536; int hl=id>>10, rem=id&1023, r=rem>>4, c8=(rem&15)<<3;
    p.v3 = *(const uint4*)((hl?bl:bh) + (size_t)off + r*st + c8); }
  return p;
}
__device__ __forceinline__ void write_tile(u16* Bt, int t, Pre4 p){
  { int id=t;      int hl=id>>10, rem=id&1023, r=rem>>4, c8=(rem&15)<<3;
    *(uint4*)(Bt + hl*(64*136) + r*136 + c8) = p.v0; }
  { int id=t+512;  int hl=id>>10, rem=id&1023, r=rem>>4, c8=(rem&15)<<3;
    *(uint4*)(Bt + hl*(64*136) + r*136 + c8) = p.v1; }
  { int id=t+1024; int hl=id>>10, rem=id&1023, r=rem>>4, c8=(rem&15)<<3;
    *(uint4*)(Bt + hl*(64*136) + r*136 + c8) = p.v2; }
  { int id=t+1536; int hl=id>>10, rem=id&1023, r=rem>>4, c8=(rem&15)<<3;
    *(uint4*)(Bt + hl*(64*136) + r*136 + c8) = p.v3; }
}
#define TSRC uvh,uvl,w1h_,w1l_,w2h_,w2l_,mw1h_,mw1l_,mw2h_,mw2l_

// =====================================================================
// k_fused: Uv/Vv GEMM + dot/norm + update MLP + apply + next-layer msg MLP
// 32 rows/block, 512 threads (8 waves: 2 row-tiles x 4 col-waves), grid 256.
// Schedule: 1-deep by-value register prefetch of the linear 22-tile weight
// stream (loads issue under the previous tile's MFMA) + named-scalar
// fragment hoists (all promotion-proof: no small arrays by pointer).
// =====================================================================
__global__ __launch_bounds__(512) void k_fused(
    const u16* __restrict__ uvh,  const u16* __restrict__ uvl,   // [256][128] (U rows 0..127, V rows 128..255)
    const u16* __restrict__ w1h_, const u16* __restrict__ w1l_,  // [128][256]
    const u16* __restrict__ w2h_, const u16* __restrict__ w2l_,  // [384][128]
    const float* __restrict__ b1, const float* __restrict__ b2,
    const u16* __restrict__ mw1h_, const u16* __restrict__ mw1l_, // [128][128] or null
    const u16* __restrict__ mw2h_, const u16* __restrict__ mw2l_, // [384][128]
    const float* __restrict__ mb1, const float* __restrict__ mb2,
    float* __restrict__ s, u16* __restrict__ s_h, u16* __restrict__ s_l,
    u16* __restrict__ v_h, u16* __restrict__ v_l,   // read + update in place
    u16* __restrict__ bufA16, u16* __restrict__ bufB16,
    float* __restrict__ out){
  // LDS regions (138 KB total, gfx950 has 160 KB/CU):
  __shared__ __align__(16) u16 AV [6*32*136];  // v rows, 3 comps x hi/lo   (51 KB, persists)
  __shared__ __align__(16) u16 Bt [2*64*136];  // B tile hi/lo, reused      (34 KB)
  __shared__ __align__(16) u16 AIb[2*32*264];  // ai hi/lo; later aL(half[32][392]) then mH hi/lo
  __shared__ __align__(16) u16 Hx [2*32*136];  // H hi/lo; later A_s (new-s hi/lo) for msg
  int t = threadIdx.x;
  int lane = t&63, w = t>>6;
  int qr = (w>>2)<<4;            // row-tile: 0 or 16
  int qw = w&3;                  // col-wave
  int l15 = lane&15, q8 = (lane>>4)<<3, qrow = (lane>>4)<<2;
  int row0 = blockIdx.x<<5;
  bool domsg = (mw1h_ != nullptr);
  const int NT = domsg ? 22 : 14;

// 3 MFMA (hh,hl,lh) against the current Bt tile at k-slice KS
#define MFMA_STEP(ACC, KS, AH, AL) { \
    bf16x8 _bh = *(const bf16x8*)&Bt[(qw*16+l15)*136 + (KS)*32 + q8]; \
    bf16x8 _bl = *(const bf16x8*)&Bt[64*136 + (qw*16+l15)*136 + (KS)*32 + q8]; \
    ACC = __builtin_amdgcn_mfma_f32_16x16x32_bf16(AH, _bh, ACC, 0,0,0); \
    ACC = __builtin_amdgcn_mfma_f32_16x16x32_bf16(AH, _bl, ACC, 0,0,0); \
    ACC = __builtin_amdgcn_mfma_f32_16x16x32_bf16(AL, _bh, ACC, 0,0,0); }

  // ---- stage A: v rows (3c x hi/lo) and the s-half of ai ----
  #pragma unroll
  for (int q=0;q<6;q++){
    int id = t + 512*q;                     // 0..3071 = 6 planes x 32 x 16
    int chl = id>>9, rem = id&511, r = rem>>4, c8 = (rem&15)<<3;
    const u16* src = ((chl&1)? v_l : v_h) + (size_t)(chl>>1)*NF + (size_t)(row0+r)*F + c8;
    *(uint4*)&AV[((size_t)chl*32 + r)*136 + c8] = *(const uint4*)src;
  }
  #pragma unroll
  for (int q=0;q<2;q++){
    int id = t + 512*q;                     // 0..1023 = 2 planes x 32 x 16
    int hl = id>>9, rem = id&511, r = rem>>4, c8 = (rem&15)<<3;
    const u16* src = (hl? s_l : s_h) + (size_t)(row0+r)*F + c8;
    *(uint4*)&AIb[(size_t)hl*32*264 + r*264 + 128 + c8] = *(const uint4*)src;
  }

  Pre4 pre = load_tile(0, t, TSRC);

  // ---- phase 1: Uv/Vv GEMM (K=128, split-bf16 hh+hl+lh) ----
  f32x4 aU[2][3], aV[2][3];
  #pragma unroll
  for (int cg=0; cg<4; cg++){               // U[0:64],U[64:128],V[0:64],V[64:128]
    __syncthreads();
    write_tile(Bt, t, pre);
    __syncthreads();
    pre = load_tile(cg+1, t, TSRC);
    f32x4 ac0, ac1, ac2;
    ac0[0]=0;ac0[1]=0;ac0[2]=0;ac0[3]=0; ac1=ac0; ac2=ac0;
    #pragma unroll
    for (int k0=0;k0<F;k0+=32){
      bf16x8 b_h = *(const bf16x8*)&Bt[(qw*16+l15)*136 + k0 + q8];
      bf16x8 b_l = *(const bf16x8*)&Bt[64*136 + (qw*16+l15)*136 + k0 + q8];
      {
        bf16x8 a_h = *(const bf16x8*)&AV[(0*32 + qr + l15)*136 + k0 + q8];
        bf16x8 a_l = *(const bf16x8*)&AV[(1*32 + qr + l15)*136 + k0 + q8];
        ac0 = __builtin_amdgcn_mfma_f32_16x16x32_bf16(a_h, b_h, ac0, 0,0,0);
        ac0 = __builtin_amdgcn_mfma_f32_16x16x32_bf16(a_h, b_l, ac0, 0,0,0);
        ac0 = __builtin_amdgcn_mfma_f32_16x16x32_bf16(a_l, b_h, ac0, 0,0,0);
      }
      {
        bf16x8 a_h = *(const bf16x8*)&AV[(2*32 + qr + l15)*136 + k0 + q8];
        bf16x8 a_l = *(const bf16x8*)&AV[(3*32 + qr + l15)*136 + k0 + q8];
        ac1 = __builtin_amdgcn_mfma_f32_16x16x32_bf16(a_h, b_h, ac1, 0,0,0);
        ac1 = __builtin_amdgcn_mfma_f32_16x16x32_bf16(a_h, b_l, ac1, 0,0,0);
        ac1 = __builtin_amdgcn_mfma_f32_16x16x32_bf16(a_l, b_h, ac1, 0,0,0);
      }
      {
        bf16x8 a_h = *(const bf16x8*)&AV[(4*32 + qr + l15)*136 + k0 + q8];
        bf16x8 a_l = *(const bf16x8*)&AV[(5*32 + qr + l15)*136 + k0 + q8];
        ac2 = __builtin_amdgcn_mfma_f32_16x16x32_bf16(a_h, b_h, ac2, 0,0,0);
        ac2 = __builtin_amdgcn_mfma_f32_16x16x32_bf16(a_h, b_l, ac2, 0,0,0);
        ac2 = __builtin_amdgcn_mfma_f32_16x16x32_bf16(a_l, b_h, ac2, 0,0,0);
      }
    }
    if (cg<2){ aU[cg][0]=ac0; aU[cg][1]=ac1; aU[cg][2]=ac2; }
    else     { aV[cg-2][0]=ac0; aV[cg-2][1]=ac1; aV[cg-2][2]=ac2; }
  }

  // ---- dot / norm in-register; norm -> ai[:,0:128] ----
  f32x4 dotf[2];
  #pragma unroll
  for (int g=0; g<2; g++){
    #pragma unroll
    for (int r=0;r<4;r++){
      float d=0.f, n2=0.f;
      #pragma unroll
      for (int c=0;c<3;c++){ d += aU[g][c][r]*aV[g][c][r]; n2 += aV[g][c][r]*aV[g][c][r]; }
      dotf[g][r]=d;
      int row = qr+qrow+r, col = g*64+qw*16+l15;
      float vn = sqrtf(n2);
      u16 h = f2bf(vn);
      AIb[row*264+col] = h;
      AIb[32*264 + row*264+col] = f2bf(vn - bf2f(h));
    }
  }
  __syncthreads();                           // norm writes visible

  // ---- phase 2: H = silu(ai @ w1 + b1)   (K=256; kc outer, cgc inner) ----
  f32x4 acc2A, acc2B;
  acc2A[0]=0;acc2A[1]=0;acc2A[2]=0;acc2A[3]=0; acc2B=acc2A;
  #pragma unroll
  for (int kc=0; kc<2; kc++){
    const int ab = (qr+l15)*264 + kc*128 + q8;
    bf16x8 a20h = *(const bf16x8*)&AIb[ab+  0];
    bf16x8 a21h = *(const bf16x8*)&AIb[ab+ 32];
    bf16x8 a22h = *(const bf16x8*)&AIb[ab+ 64];
    bf16x8 a23h = *(const bf16x8*)&AIb[ab+ 96];
    bf16x8 a20l = *(const bf16x8*)&AIb[32*264+ab+  0];
    bf16x8 a21l = *(const bf16x8*)&AIb[32*264+ab+ 32];
    bf16x8 a22l = *(const bf16x8*)&AIb[32*264+ab+ 64];
    bf16x8 a23l = *(const bf16x8*)&AIb[32*264+ab+ 96];
    // cgc = 0
    __syncthreads();
    write_tile(Bt, t, pre);
    __syncthreads();
    pre = load_tile(4 + kc*2 + 1, t, TSRC);
    MFMA_STEP(acc2A, 0, a20h, a20l);
    MFMA_STEP(acc2A, 1, a21h, a21l);
    MFMA_STEP(acc2A, 2, a22h, a22l);
    MFMA_STEP(acc2A, 3, a23h, a23l);
    // cgc = 1
    __syncthreads();
    write_tile(Bt, t, pre);
    __syncthreads();
    pre = load_tile(4 + kc*2 + 2, t, TSRC);
    MFMA_STEP(acc2B, 0, a20h, a20l);
    MFMA_STEP(acc2B, 1, a21h, a21l);
    MFMA_STEP(acc2B, 2, a22h, a22l);
    MFMA_STEP(acc2B, 3, a23h, a23l);
  }
  {
    int colA = qw*16 + l15;
    float bbA = b1[colA], bbB = b1[64+colA];
    #pragma unroll
    for (int r=0;r<4;r++){
      float vA = silu_f(acc2A[r] + bbA);
      u16 hA = f2bf(vA);
      Hx[(qr+qrow+r)*136 + colA] = hA;
      Hx[32*136 + (qr+qrow+r)*136 + colA] = f2bf(vA - bf2f(hA));
      float vB = silu_f(acc2B[r] + bbB);
      u16 hB = f2bf(vB);
      Hx[(qr+qrow+r)*136 + 64+colA] = hB;
      Hx[32*136 + (qr+qrow+r)*136 + 64+colA] = f2bf(vB - bf2f(hB));
    }
  }
  __syncthreads();                           // H visible

  // ---- phase 3: a = H @ w2 + b2 -> aL (half, aliases ai region) ----
  bf16x8 ha0h = *(const bf16x8*)&Hx[(qr+l15)*136 +  0 + q8];
  bf16x8 ha1h = *(const bf16x8*)&Hx[(qr+l15)*136 + 32 + q8];
  bf16x8 ha2h = *(const bf16x8*)&Hx[(qr+l15)*136 + 64 + q8];
  bf16x8 ha3h = *(const bf16x8*)&Hx[(qr+l15)*136 + 96 + q8];
  bf16x8 ha0l = *(const bf16x8*)&Hx[32*136 + (qr+l15)*136 +  0 + q8];
  bf16x8 ha1l = *(const bf16x8*)&Hx[32*136 + (qr+l15)*136 + 32 + q8];
  bf16x8 ha2l = *(const bf16x8*)&Hx[32*136 + (qr+l15)*136 + 64 + q8];
  bf16x8 ha3l = *(const bf16x8*)&Hx[32*136 + (qr+l15)*136 + 96 + q8];
  __half* aL = (__half*)AIb;                 // [32][392]; ai reads are done
  #pragma unroll
  for (int cg=0; cg<6; cg++){
    __syncthreads();
    write_tile(Bt, t, pre);
    __syncthreads();
    if (9+cg < NT)
      pre = load_tile(9+cg, t, TSRC);
    f32x4 acc; acc[0]=0;acc[1]=0;acc[2]=0;acc[3]=0;
    MFMA_STEP(acc, 0, ha0h, ha0l);
    MFMA_STEP(acc, 1, ha1h, ha1l);
    MFMA_STEP(acc, 2, ha2h, ha2l);
    MFMA_STEP(acc, 3, ha3h, ha3l);
    int gc = cg*64 + qw*16 + l15;
    float bb = b2[gc];
    #pragma unroll
    for (int r=0;r<4;r++)
      aL[(qr+qrow+r)*392 + gc] = __float2half(acc[r] + bb);
  }
  __syncthreads();

  // ---- epilogue in fragment layout: s,v update + bufA/B v-packs + A_s for msg ----
  #pragma unroll
  for (int g=0; g<2; g++){
    #pragma unroll
    for (int r=0; r<4; r++){
      int row = qr+qrow+r;
      int col = g*64+qw*16+l15;
      int grow = row0+row;
      size_t i = (size_t)grow*F + col;
      float avv = __half2float(aL[row*392 + col]);
      float asv = __half2float(aL[row*392 + F + col]);
      float ass = __half2float(aL[row*392 + 2*F + col]);
      float sv = s[i] + ass + asv*dotf[g][r];
      s[i] = sv;
      u16 hb = f2bf(sv); u16 lb = f2bf(sv - bf2f(hb));
      s_h[i]=hb; s_l[i]=lb;
      float nv[3];
      #pragma unroll
      for (int c=0;c<3;c++){
        float vold = bf2f(AV[((2*c)*32+row)*136+col]) + bf2f(AV[((2*c+1)*32+row)*136+col]);
        nv[c] = vold + aU[g][c][r]*avv;
      }
      u16 h0=f2bf(nv[0]), h1=f2bf(nv[1]), h2=f2bf(nv[2]);
      v_h[i]=h0; v_h[NF+i]=h1; v_h[2*(size_t)NF+i]=h2;
      v_l[i]=f2bf(nv[0]-bf2f(h0)); v_l[NF+i]=f2bf(nv[1]-bf2f(h1)); v_l[2*(size_t)NF+i]=f2bf(nv[2]-bf2f(h2));
      bufA16[i*4+2]=h0; bufA16[i*4+3]=h1; bufB16[i*2+1]=h2;
      if (out){
        out[i] = sv;
        out[NF + i*3 + 0] = nv[0];
        out[NF + i*3 + 1] = nv[1];
        out[NF + i*3 + 2] = nv[2];
      }
      if (domsg){                                  // A_s aliases Hx (H reads done)
        Hx[row*136+col] = hb;
        Hx[32*136 + row*136+col] = lb;
      }
    }
  }

  // ---- phase 4 (layers 0,1): next layer's msg MLP, phi -> bufA/bufB ----
  if (domsg){
    __syncthreads();                         // A_s visible (also: all aL reads done)
    // mH = silu(new_s @ mw1 + mb1)  (K=128); mH aliases AIb
    bf16x8 sa0h = *(const bf16x8*)&Hx[(qr+l15)*136 +  0 + q8];
    bf16x8 sa1h = *(const bf16x8*)&Hx[(qr+l15)*136 + 32 + q8];
    bf16x8 sa2h = *(const bf16x8*)&Hx[(qr+l15)*136 + 64 + q8];
    bf16x8 sa3h = *(const bf16x8*)&Hx[(qr+l15)*136 + 96 + q8];
    bf16x8 sa0l = *(const bf16x8*)&Hx[32*136 + (qr+l15)*136 +  0 + q8];
    bf16x8 sa1l = *(const bf16x8*)&Hx[32*136 + (qr+l15)*136 + 32 + q8];
    bf16x8 sa2l = *(const bf16x8*)&Hx[32*136 + (qr+l15)*136 + 64 + q8];
    bf16x8 sa3l = *(const bf16x8*)&Hx[32*136 + (qr+l15)*136 + 96 + q8];
    f32x4 acc4A, acc4B;
    acc4A[0]=0;acc4A[1]=0;acc4A[2]=0;acc4A[3]=0; acc4B=acc4A;
    // cgc = 0
    __syncthreads();
    write_tile(Bt, t, pre);
    __syncthreads();
    pre = load_tile(15, t, TSRC);
    MFMA_STEP(acc4A, 0, sa0h, sa0l);
    MFMA_STEP(acc4A, 1, sa1h, sa1l);
    MFMA_STEP(acc4A, 2, sa2h, sa2l);
    MFMA_STEP(acc4A, 3, sa3h, sa3l);
    // cgc = 1
    __syncthreads();
    write_tile(Bt, t, pre);
    __syncthreads();
    pre = load_tile(16, t, TSRC);
    MFMA_STEP(acc4B, 0, sa0h, sa0l);
    MFMA_STEP(acc4B, 1, sa1h, sa1l);
    MFMA_STEP(acc4B, 2, sa2h, sa2l);
    MFMA_STEP(acc4B, 3, sa3h, sa3l);
    {
      int colA = qw*16 + l15;
      float bbA = mb1[colA], bbB = mb1[64+colA];
      #pragma unroll
      for (int r=0;r<4;r++){
        float vA = silu_f(acc4A[r] + bbA);
        u16 hA = f2bf(vA);
        AIb[(qr+qrow+r)*136 + colA] = hA;                 // mH hi (stride 136)
        AIb[32*136 + (qr+qrow+r)*136 + colA] = f2bf(vA - bf2f(hA));
        float vB = silu_f(acc4B[r] + bbB);
        u16 hB = f2bf(vB);
        AIb[(qr+qrow+r)*136 + 64+colA] = hB;
        AIb[32*136 + (qr+qrow+r)*136 + 64+colA] = f2bf(vB - bf2f(hB));
      }
    }
    __syncthreads();                         // mH visible

    // phi = mH @ mw2 + mb2 -> bufA/bufB
    bf16x8 mh0h = *(const bf16x8*)&AIb[(qr+l15)*136 +  0 + q8];
    bf16x8 mh1h = *(const bf16x8*)&AIb[(qr+l15)*136 + 32 + q8];
    bf16x8 mh2h = *(const bf16x8*)&AIb[(qr+l15)*136 + 64 + q8];
    bf16x8 mh3h = *(const bf16x8*)&AIb[(qr+l15)*136 + 96 + q8];
    bf16x8 mh0l = *(const bf16x8*)&AIb[32*136 + (qr+l15)*136 +  0 + q8];
    bf16x8 mh1l = *(const bf16x8*)&AIb[32*136 + (qr+l15)*136 + 32 + q8];
    bf16x8 mh2l = *(const bf16x8*)&AIb[32*136 + (qr+l15)*136 + 64 + q8];
    bf16x8 mh3l = *(const bf16x8*)&AIb[32*136 + (qr+l15)*136 + 96 + q8];
    #pragma unroll
    for (int cg=0; cg<6; cg++){
      __syncthreads();
      write_tile(Bt, t, pre);
      __syncthreads();
      if (17+cg < NT)
        pre = load_tile(17+cg, t, TSRC);
      f32x4 acc; acc[0]=0;acc[1]=0;acc[2]=0;acc[3]=0;
      MFMA_STEP(acc, 0, mh0h, mh0l);
      MFMA_STEP(acc, 1, mh1h, mh1l);
      MFMA_STEP(acc, 2, mh2h, mh2l);
      MFMA_STEP(acc, 3, mh3h, mh3l);
      int gc = cg*64 + qw*16 + l15;
      float bb = mb2[gc];
      #pragma unroll
      for (int r=0;r<4;r++){
        int grow = row0 + qr + qrow + r;
        u16 v16 = f2bf(acc[r] + bb);
        size_t rowo = (size_t)grow*F;
        if (gc < F)        bufA16[(rowo + gc)*4 + 0]     = v16;  // phi_vv
        else if (gc < 2*F) bufA16[(rowo + gc - F)*4 + 1] = v16;  // phi_ss
        else               bufB16[(rowo + gc - 2*F)*2]   = v16;  // phi_vs
      }
    }
  }
#undef MFMA_STEP
}

// ------------------------------------------------------------------ launch
extern "C" void kernel_launch(void* const* d_in, const int* in_sizes, int n_in,
                              void* d_out, int out_size, void* d_ws, size_t ws_size,
                              hipStream_t stream) {
  const int* atoms   = (const int*)d_in[0];
  const int* idxj    = (const int*)d_in[2];

  float* W = (float*)d_ws;
  size_t off = 64;
  int* flag = (int*)d_ws;
  #define ALLOCF(name, cnt) float* name = W+off; off += (((cnt)+63)&~(size_t)63)
  #define ALLOCU(name, cnt) u16* name = (u16*)(W+off); off += ((((cnt)+1)/2+63)&~(size_t)63)
  ALLOCF(c_mb1, NLAYER*F);
  ALLOCF(c_mb2, NLAYER*F3);
  ALLOCF(c_b1,  NLAYER*F);
  ALLOCF(c_b2,  NLAYER*F3);
  unsigned* c_rwp2 = (unsigned*)(W+off); off += ((NLAYER*11*F3+63)&~(size_t)63);
  uint4* edata = (uint4*)(W+off); off += (size_t)NEDGE*16;  // E x 64B = E*16 floats
  ALLOCU(w_mw1h, NLAYER*F*F);   ALLOCU(w_mw1l, NLAYER*F*F);
  ALLOCU(w_mw2h, NLAYER*F*F3);  ALLOCU(w_mw2l, NLAYER*F*F3);
  ALLOCU(w_uvh,  NLAYER*256*F); ALLOCU(w_uvl,  NLAYER*256*F);
  ALLOCU(w_w1h,  NLAYER*F*256); ALLOCU(w_w1l,  NLAYER*F*256);
  ALLOCU(w_w2h,  NLAYER*F*F3);  ALLOCU(w_w2l,  NLAYER*F*F3);
  uint2* bufA = (uint2*)(W+off); off += (size_t)2*NF;       // NF x 8B
  unsigned* bufB = (unsigned*)(W+off); off += (size_t)NF;   // NF x 4B
  ALLOCU(p0h, (size_t)3*NF); ALLOCU(p0l, (size_t)3*NF);
  ALLOCU(p1h, (size_t)3*NF); ALLOCU(p1l, (size_t)3*NF);
  ALLOCU(s_h,  NF); ALLOCU(s_l,  NF);
  ALLOCF(s,    NF);

  k_detect<<<1, 64, 0, stream>>>((const u16*)d_in[4], flag);
  k_prep<<<(PREP_TOTAL+255)/256, 256, 0, stream>>>(
      d_in[7], d_in[9], d_in[15], d_in[17],
      d_in[10], d_in[11],
      d_in[6], d_in[8], d_in[14], d_in[16],
      d_in[12], d_in[13],
      d_in[4], d_in[3], idxj,
      atoms, d_in[5],
      c_mb1, c_mb2, c_b1, c_b2, c_rwp2,
      w_mw1h, w_mw1l, w_mw2h, w_mw2l, w_w1h, w_w1l,
      w_w2h, w_w2l, w_uvh, w_uvl, edata,
      s, s_h, s_l, p0h, p0l, (u16*)bufA, (u16*)bufB, flag);

  // layer-0 message MLP (later layers get phi from k_fused's tail)
  k_msg<<<N_NODES/16, 256, 0, stream>>>(
      s_h, s_l,
      w_mw1h, w_mw1l, w_mw2h, w_mw2l,
      c_mb1, c_mb2,
      (u16*)bufA, (u16*)bufB);

  for (int l=0; l<NLAYER; l++){
    u16* vih = (l & 1) ? p1h : p0h;
    u16* vil = (l & 1) ? p1l : p0l;
    u16* voh = (l & 1) ? p0h : p1h;
    u16* vol = (l & 1) ? p0l : p1l;
    k_agg<<<N_NODES/2, 256, 0, stream>>>(
        edata, bufA, bufB, c_rwp2 + (size_t)l*11*F3,
        vih, vil, voh, vol, s, s_h, s_l);
    int ln = l + 1;
    int domsg = (l < NLAYER-1);
    k_fused<<<N_NODES/32, 512, 0, stream>>>(
        w_uvh + (size_t)l*256*F, w_uvl + (size_t)l*256*F,
        w_w1h + (size_t)l*F*256, w_w1l + (size_t)l*F*256,
        w_w2h + (size_t)l*F*F3,  w_w2l + (size_t)l*F*F3,
        c_b1 + (size_t)l*F, c_b2 + (size_t)l*F3,
        domsg ? w_mw1h + (size_t)ln*F*F  : nullptr,
        domsg ? w_mw1l + (size_t)ln*F*F  : nullptr,
        domsg ? w_mw2h + (size_t)ln*F*F3 : nullptr,
        domsg ? w_mw2l + (size_t)ln*F*F3 : nullptr,
        domsg ? c_mb1 + (size_t)ln*F  : nullptr,
        domsg ? c_mb2 + (size_t)ln*F3 : nullptr,
        s, s_h, s_l, voh, vol,
        (u16*)bufA, (u16*)bufB,
        (l == NLAYER-1) ? (float*)d_out : nullptr);
  }
}